// Round 1
// baseline (356.725 us; speedup 1.0000x reference)
//
#include <hip/hip_runtime.h>

#define RESO 192
#define DATA_DIM 28   // BASIS_DIM*3 + 1 = 28

// One point per 32-lane group; lane c (< 28) owns channel c.
// Corner data gathers are coalesced 112B segments; link/point loads are
// wave-uniform broadcasts.
__global__ __launch_bounds__(256) void trilerp_kernel(
    const float* __restrict__ points,
    const float* __restrict__ data,
    const int*   __restrict__ links,
    const float* __restrict__ offset,
    const float* __restrict__ scaling,
    float*       __restrict__ out,
    int npts)
{
    const int gid   = blockIdx.x * blockDim.x + threadIdx.x;
    const int point = gid >> 5;
    const int sub   = threadIdx.x & 31;
    if (point >= npts) return;

    // Broadcast loads (same address across the 32-lane group)
    const float px = points[point * 3 + 0];
    const float py = points[point * 3 + 1];
    const float pz = points[point * 3 + 2];

    const float g = (float)RESO;

    float p0 = px * (scaling[0] * g) + (offset[0] * g - 0.5f);
    float p1 = py * (scaling[1] * g) + (offset[1] * g - 0.5f);
    float p2 = pz * (scaling[2] * g) + (offset[2] * g - 0.5f);

    p0 = fminf(fmaxf(p0, 0.0f), g - 1.0f);
    p1 = fminf(fmaxf(p1, 0.0f), g - 1.0f);
    p2 = fminf(fmaxf(p2, 0.0f), g - 1.0f);

    const int lx = min((int)p0, RESO - 2);
    const int ly = min((int)p1, RESO - 2);
    const int lz = min((int)p2, RESO - 2);

    const float wbx = p0 - (float)lx, wax = 1.0f - wbx;
    const float wby = p1 - (float)ly, way = 1.0f - wby;
    const float wbz = p2 - (float)lz, waz = 1.0f - wbz;

    // 8 corner links (uniform across the group -> broadcast transactions)
    const int base = (lx * RESO + ly) * RESO + lz;
    const int lk000 = links[base];
    const int lk001 = links[base + 1];
    const int lk010 = links[base + RESO];
    const int lk011 = links[base + RESO + 1];
    const int lk100 = links[base + RESO * RESO];
    const int lk101 = links[base + RESO * RESO + 1];
    const int lk110 = links[base + RESO * RESO + RESO];
    const int lk111 = links[base + RESO * RESO + RESO + 1];

    if (sub >= DATA_DIM) return;

    // Trilinear corner weights
    const float w000 = wax * way * waz;
    const float w001 = wax * way * wbz;
    const float w010 = wax * wby * waz;
    const float w011 = wax * wby * wbz;
    const float w100 = wbx * way * waz;
    const float w101 = wbx * way * wbz;
    const float w110 = wbx * wby * waz;
    const float w111 = wbx * wby * wbz;

    float acc = 0.0f;
    if (lk000 >= 0) acc += w000 * data[lk000 * DATA_DIM + sub];
    if (lk001 >= 0) acc += w001 * data[lk001 * DATA_DIM + sub];
    if (lk010 >= 0) acc += w010 * data[lk010 * DATA_DIM + sub];
    if (lk011 >= 0) acc += w011 * data[lk011 * DATA_DIM + sub];
    if (lk100 >= 0) acc += w100 * data[lk100 * DATA_DIM + sub];
    if (lk101 >= 0) acc += w101 * data[lk101 * DATA_DIM + sub];
    if (lk110 >= 0) acc += w110 * data[lk110 * DATA_DIM + sub];
    if (lk111 >= 0) acc += w111 * data[lk111 * DATA_DIM + sub];

    out[point * DATA_DIM + sub] = acc;
}

extern "C" void kernel_launch(void* const* d_in, const int* in_sizes, int n_in,
                              void* d_out, int out_size, void* d_ws, size_t ws_size,
                              hipStream_t stream) {
    const float* points  = (const float*)d_in[0];
    const float* data    = (const float*)d_in[1];
    const int*   links   = (const int*)d_in[2];
    const float* offset  = (const float*)d_in[3];
    const float* scaling = (const float*)d_in[4];
    float* out = (float*)d_out;

    const int npts = in_sizes[0] / 3;

    // 32 lanes per point, 256 threads/block -> 8 points per block
    const int blocks = (npts + 7) / 8;
    trilerp_kernel<<<blocks, 256, 0, stream>>>(points, data, links, offset,
                                               scaling, out, npts);
}

// Round 3
// 225.985 us; speedup vs baseline: 1.5785x; 1.5785x over previous
//
#include <hip/hip_runtime.h>

#define RESO 192
#define DATA_DIM 28   // BASIS_DIM*3 + 1 = 28

typedef float f4 __attribute__((ext_vector_type(4)));  // native vector type

// One point per 8-lane group; lane j (< 7) owns channels 4j..4j+3 (float4).
// 8 points per wave -> 64 random 112B corner segments in flight per wave.
__global__ __launch_bounds__(256) void trilerp_kernel(
    const float* __restrict__ points,
    const float* __restrict__ data,
    const int*   __restrict__ links,
    const float* __restrict__ offset,
    const float* __restrict__ scaling,
    float*       __restrict__ out,
    int npts)
{
    const int gid   = blockIdx.x * blockDim.x + threadIdx.x;
    const int point = gid >> 3;
    const int sub   = threadIdx.x & 7;
    if (point >= npts) return;

    // Same address across the 8-lane group -> broadcast-coalesced
    const float px = points[point * 3 + 0];
    const float py = points[point * 3 + 1];
    const float pz = points[point * 3 + 2];

    const float g = (float)RESO;

    float p0 = px * (scaling[0] * g) + (offset[0] * g - 0.5f);
    float p1 = py * (scaling[1] * g) + (offset[1] * g - 0.5f);
    float p2 = pz * (scaling[2] * g) + (offset[2] * g - 0.5f);

    p0 = fminf(fmaxf(p0, 0.0f), g - 1.0f);
    p1 = fminf(fmaxf(p1, 0.0f), g - 1.0f);
    p2 = fminf(fmaxf(p2, 0.0f), g - 1.0f);

    const int lx = min((int)p0, RESO - 2);
    const int ly = min((int)p1, RESO - 2);
    const int lz = min((int)p2, RESO - 2);

    const float wbx = p0 - (float)lx, wax = 1.0f - wbx;
    const float wby = p1 - (float)ly, way = 1.0f - wby;
    const float wbz = p2 - (float)lz, waz = 1.0f - wbz;

    const int base = (lx * RESO + ly) * RESO + lz;
    const int lk000 = links[base];
    const int lk001 = links[base + 1];
    const int lk010 = links[base + RESO];
    const int lk011 = links[base + RESO + 1];
    const int lk100 = links[base + RESO * RESO];
    const int lk101 = links[base + RESO * RESO + 1];
    const int lk110 = links[base + RESO * RESO + RESO];
    const int lk111 = links[base + RESO * RESO + RESO + 1];

    if (sub >= 7) return;   // lane 7 idle; lanes 0..6 cover 28 channels

    const float w000 = wax * way * waz;
    const float w001 = wax * way * wbz;
    const float w010 = wax * wby * waz;
    const float w011 = wax * wby * wbz;
    const float w100 = wbx * way * waz;
    const float w101 = wbx * way * wbz;
    const float w110 = wbx * wby * waz;
    const float w111 = wbx * wby * wbz;

    const int ch = sub * 4;   // first channel this lane owns

    f4 acc = (f4)(0.0f);

    // 8 independent float4 gathers (rows are 16B-aligned: 112 = 7*16)
    #define CORNER(LK, W)                                                     \
        if ((LK) >= 0) {                                                      \
            const f4 v = *reinterpret_cast<const f4*>(                        \
                data + (size_t)(LK) * DATA_DIM + ch);                         \
            acc += (W) * v;                                                   \
        }

    CORNER(lk000, w000)
    CORNER(lk001, w001)
    CORNER(lk010, w010)
    CORNER(lk011, w011)
    CORNER(lk100, w100)
    CORNER(lk101, w101)
    CORNER(lk110, w110)
    CORNER(lk111, w111)
    #undef CORNER

    // Streaming store; keep L2/L3 for the data table
    __builtin_nontemporal_store(acc,
        reinterpret_cast<f4*>(out + (size_t)point * DATA_DIM + ch));
}

extern "C" void kernel_launch(void* const* d_in, const int* in_sizes, int n_in,
                              void* d_out, int out_size, void* d_ws, size_t ws_size,
                              hipStream_t stream) {
    const float* points  = (const float*)d_in[0];
    const float* data    = (const float*)d_in[1];
    const int*   links   = (const int*)d_in[2];
    const float* offset  = (const float*)d_in[3];
    const float* scaling = (const float*)d_in[4];
    float* out = (float*)d_out;

    const int npts = in_sizes[0] / 3;

    // 8 lanes per point, 256 threads/block -> 32 points per block
    const int blocks = (npts + 31) / 32;
    trilerp_kernel<<<blocks, 256, 0, stream>>>(points, data, links, offset,
                                               scaling, out, npts);
}